// Round 18
// baseline (189.354 us; speedup 1.0000x reference)
//
#include <hip/hip_runtime.h>
#include <cstdint>

// GIN: N=50000, D=128, E=800000, L=3.
// per layer: agg = x + gather-sum over CSR(dst); x' = relu(relu(agg@W1+b1)@W2+b2)
// CSR built once per launch with ZERO global atomics (rounds 8-10 lesson:
// scattered global atomics cap at ~16 line-ops/ns regardless of scope/layout).
// Round-18: r16 state (r17 perm REVERTED - regressed) plus:
//  - gather __launch_bounds__(256,4): VGPR budget 128 so the 8-row batch stays
//    in flight (r17 lesson: at default the compiler collapsed to ~2-3 rows,
//    VGPR=20 -> latency-bound)
//  - partition pad-base 8-aligned -> neighbor indices loaded as 2x int4
//  - k_gbase deleted: scat/fin recompute the 98x391 prefix in-block (L2-hot)
// Gather = 16 nodes/block x 16 lanes, branch-free 8-wide padded loop.
// GEMM = 512-thr, 128 rows, dual-W LDS staging (69.6 KB, 2 blocks/CU).

constexpr int N = 50000;
constexpr int D = 128;
constexpr int E = 800000;
constexpr int L = 3;
constexpr int WROW = 136;                 // padded LDS row (f16): 2-way banks, free
constexpr int PSH = 9;                    // partition shift: 512 nodes
constexpr int PN = 1 << PSH;              // 512
constexpr int K = (N + PN - 1) >> PSH;    // 98 partitions
constexpr int SLACK = 7 * PN + 8;         // padded capacity slack per partition
constexpr int ABLK = 2048;                // edges per A-block
constexpr int NAB = (E + ABLK - 1) / ABLK;  // 391

typedef _Float16 f16;
typedef _Float16 f16x8 __attribute__((ext_vector_type(8)));
typedef float f32x4 __attribute__((ext_vector_type(4)));

// ---- edge index load (handles int32 or int64 storage) ----
__device__ __forceinline__ bool ei_is64(const int* ei) {
  return (ei[1] == 0) && (ei[3] == 0) && (ei[5] == 0);
}
__device__ __forceinline__ int ei_src(const int* ei, int e, bool is64) {
  return is64 ? ei[2 * (size_t)e] : ei[e];
}
__device__ __forceinline__ int ei_dst(const int* ei, int e, bool is64) {
  return is64 ? ei[2 * ((size_t)E + e)] : ei[(size_t)E + e];
}

// ---------------- merged one-time prep: wprep + cvt + edge pass A1 + zrow ----
// grid = 384 + 3125 + NAB + 1 blocks.
__global__ __launch_bounds__(256) void k_init(const float* __restrict__ x0,
                                              const int* __restrict__ ei,
                                              const float* __restrict__ W1,
                                              const float* __restrict__ W2,
                                              f16* __restrict__ Wt,
                                              f16* __restrict__ xh,
                                              int2* __restrict__ srcdst,
                                              int* __restrict__ gcnt) {
  __shared__ int hist[K];
  const int bid = blockIdx.x;
  if (bid < 384) {
    // Wt[m][c][k] = Wsrc[m][k][c] as f16 (first L from W1, rest W2)
    int i = bid * 256 + threadIdx.x;
    int m = i >> 14;
    int c = (i >> 7) & 127;
    int k = i & 127;
    const float* src = (m < L) ? (W1 + (size_t)m * D * D)
                               : (W2 + (size_t)(m - L) * D * D);
    Wt[i] = (f16)src[(size_t)k * D + c];
  } else if (bid < 384 + 3125) {
    // x0 f32 -> xh f16, 8 elems/thread
    int i = (bid - 384) * 256 + threadIdx.x;
    float4 v0 = *(const float4*)(x0 + (size_t)i * 8);
    float4 v1 = *(const float4*)(x0 + (size_t)i * 8 + 4);
    f16x8 o = {(f16)v0.x, (f16)v0.y, (f16)v0.z, (f16)v0.w,
               (f16)v1.x, (f16)v1.y, (f16)v1.z, (f16)v1.w};
    *(f16x8*)(xh + (size_t)i * 8) = o;
  } else if (bid < 384 + 3125 + NAB) {
    // edges -> int2(src,dst) + LDS partition histogram (no global atomics)
    const int b = bid - (384 + 3125);
    for (int i = threadIdx.x; i < K; i += 256) hist[i] = 0;
    __syncthreads();
    const int base = b * ABLK;
    const int nHere = min(ABLK, E - base);
    bool is64 = ei_is64(ei);
#pragma unroll
    for (int r = 0; r < ABLK / 256; ++r) {
      int idx = r * 256 + threadIdx.x;
      if (idx < nHere) {
        int e = base + idx;
        int s = ei_src(ei, e, is64);
        int d = ei_dst(ei, e, is64);
        srcdst[e] = make_int2(s, d);
        atomicAdd(&hist[d >> PSH], 1);  // LDS atomic
      }
    }
    __syncthreads();
    for (int i = threadIdx.x; i < K; i += 256) gcnt[i * NAB + b] = hist[i];
  } else {
    // zero row N of xh (dummy gather target for padded neighbor lists)
    if (threadIdx.x < 16)
      *(f16x8*)(xh + (size_t)N * D + threadIdx.x * 8) = (f16x8){};
  }
}

// compute, in-block from gcnt: pb[] (partition bases) and optionally each
// partition's exclusive prefix up to block b (own[]). gcnt is 153KB, L2-hot.
__device__ __forceinline__ void bases_inblock(const int* __restrict__ gcnt,
                                              int upto_b,  // -1: totals only
                                              int* __restrict__ pb,
                                              int* __restrict__ own) {
  const int tid = threadIdx.x;
  if (tid < K) {
    int tot = 0, ow = 0;
    const int* row = gcnt + tid * NAB;
    for (int i = 0; i < NAB; ++i) {
      int v = row[i];
      tot += v;
      if (i < upto_b) ow += v;
    }
    pb[tid] = tot;
    if (own) own[tid] = ow;
  }
  __syncthreads();
  if (tid == 0) {
    int r = 0;
    for (int i = 0; i < K; ++i) {
      int v = pb[i];
      pb[i] = r;
      r += v;
    }
  }
  __syncthreads();
}

// ---------------- scatter edges into partition-contiguous part[] ----------------
__global__ __launch_bounds__(256) void k_scat(const int2* __restrict__ srcdst,
                                              const int* __restrict__ gcnt,
                                              int2* __restrict__ part) {
  __shared__ int rankc[K];
  __shared__ int pb[K];
  __shared__ int own[K];
  const int b = blockIdx.x;
  const int tid = threadIdx.x;
  for (int i = tid; i < K; i += 256) rankc[i] = 0;
  bases_inblock(gcnt, b, pb, own);
  const int base = b * ABLK;
  const int nHere = min(ABLK, E - base);
#pragma unroll
  for (int r = 0; r < ABLK / 256; ++r) {
    int idx = r * 256 + tid;
    if (idx < nHere) {
      int2 sd = srcdst[base + idx];
      int p = sd.y >> PSH;
      int lr = atomicAdd(&rankc[p], 1);  // LDS atomic
      part[pb[p] + own[p] + lr] = sd;
    }
  }
}

// ---------------- finalize: padded offpe + windowed ssrc scatter -------
// node n: ssrc[offpe[n].x .. offpe[n].y) padded to x8 (pads -> zero row N).
// Partition p's padded window starts at align8(pb[p]) + p*SLACK (16B-aligned
// so the gather can load indices as int4).
__global__ __launch_bounds__(256) void k_fin(const int2* __restrict__ part,
                                             const int* __restrict__ gcnt,
                                             int2* __restrict__ offpe,
                                             int* __restrict__ ssrc) {
  __shared__ int hist[PN];
  __shared__ int bbase[PN];
  __shared__ int rc[PN];
  __shared__ int s[256];
  __shared__ int pb[K];
  __shared__ int psz[K];
  __shared__ int carry;
  const int p = blockIdx.x;
  const int tid = threadIdx.x;
  const int lo = p << PSH;
  const int nn = min(PN, N - lo);
  for (int i = tid; i < PN; i += 256) { hist[i] = 0; rc[i] = 0; }
  if (tid == 0) carry = 0;
  // per-partition totals (before pb is scanned in-place)
  if (tid < K) {
    int tot = 0;
    const int* row = gcnt + tid * NAB;
    for (int i = 0; i < NAB; ++i) tot += row[i];
    psz[tid] = tot;
  }
  bases_inblock(gcnt, -1, pb, nullptr);
  const int ebeg = pb[p], eend = pb[p] + psz[p];
  const int padbase = ((pb[p] + 7) & ~7) + p * SLACK;
  for (int e = ebeg + tid; e < eend; e += 256)
    atomicAdd(&hist[part[e].y - lo], 1);  // LDS atomic
  __syncthreads();
  // exclusive scan of PADDED degrees -> bbase
  for (int chunk = 0; chunk < PN / 256; ++chunk) {
    int i = chunk * 256 + tid;
    int v = (hist[i] + 7) & ~7;  // padded degree
    s[tid] = v;
    __syncthreads();
#pragma unroll
    for (int o = 1; o < 256; o <<= 1) {
      int t = (tid >= o) ? s[tid - o] : 0;
      __syncthreads();
      s[tid] += t;
      __syncthreads();
    }
    bbase[i] = s[tid] - v + carry;
    __syncthreads();
    if (tid == 255) carry = carry + s[255];
    __syncthreads();
  }
  // offpe + pad fill
  for (int i = tid; i < nn; i += 256) {
    int st = padbase + bbase[i];
    int deg = hist[i];
    int pd = (deg + 7) & ~7;
    offpe[lo + i] = make_int2(st, st + pd);
    for (int j = deg; j < pd; ++j) ssrc[st + j] = N;  // dummy -> zero row
  }
  __syncthreads();
  // scatter real entries
  for (int e = ebeg + tid; e < eend; e += 256) {
    int2 sd = part[e];
    int b = sd.y - lo;
    int r = atomicAdd(&rc[b], 1);  // LDS atomic
    ssrc[padbase + bbase[b] + r] = sd.x;
  }
}

// ---------------- gather-aggregate (f16): agg[n] = x[n] + sum_{j} x[src_j]
// 16 nodes/block x 16 lanes; branch-free 8-wide padded loop; indices via
// 2x int4. launch_bounds(256,4) -> VGPR budget 128 so all 8 row loads stay
// in flight (r17 lesson: default schedule collapsed to ~2-3, VGPR=20).
__global__ __launch_bounds__(256, 4) void k_gather_f16(const f16* __restrict__ x,
                                                       const int2* __restrict__ offpe,
                                                       const int* __restrict__ ssrc,
                                                       f16* __restrict__ agg) {
  const int n = blockIdx.x * 16 + (threadIdx.x >> 4);
  const int d0 = (threadIdx.x & 15) << 3;
  f16x8 v = *(const f16x8*)(x + (size_t)n * D + d0);
  float acc[8];
#pragma unroll
  for (int j = 0; j < 8; ++j) acc[j] = (float)v[j];
  const int2 oe = offpe[n];
  for (int p = oe.x; p < oe.y; p += 8) {
    int4 sa = *(const int4*)(ssrc + p);
    int4 sb = *(const int4*)(ssrc + p + 4);
    f16x8 u0 = *(const f16x8*)(x + (size_t)sa.x * D + d0);
    f16x8 u1 = *(const f16x8*)(x + (size_t)sa.y * D + d0);
    f16x8 u2 = *(const f16x8*)(x + (size_t)sa.z * D + d0);
    f16x8 u3 = *(const f16x8*)(x + (size_t)sa.w * D + d0);
    f16x8 u4 = *(const f16x8*)(x + (size_t)sb.x * D + d0);
    f16x8 u5 = *(const f16x8*)(x + (size_t)sb.y * D + d0);
    f16x8 u6 = *(const f16x8*)(x + (size_t)sb.z * D + d0);
    f16x8 u7 = *(const f16x8*)(x + (size_t)sb.w * D + d0);
#pragma unroll
    for (int j = 0; j < 8; ++j)
      acc[j] += (float)u0[j] + (float)u1[j] + (float)u2[j] + (float)u3[j] +
                (float)u4[j] + (float)u5[j] + (float)u6[j] + (float)u7[j];
  }
  f16x8 o;
#pragma unroll
  for (int j = 0; j < 8; ++j) o[j] = (f16)acc[j];
  *(f16x8*)(agg + (size_t)n * D + d0) = o;
}

// ---------------- fused double MFMA GEMM + bias + ReLU ----------------
// x' = relu(relu(A@W1+b1)@W2+b2). A f16 row-major; Wt* f16 [col][k].
// Block: 512 thr = 8 waves, 128 rows (16/wave). Dual-W LDS (69.6 KB,
// 2 blocks/CU -> 16 waves/CU = 4/SIMD). h (128x136 f16 = 34.8 KB) reuses
// W1's retired buffer. Intermediate layers write f16; last layer f32 only.
__global__ __launch_bounds__(512) void k_gemm_fused(const f16* __restrict__ A,
                                                    const f16* __restrict__ Wt1,
                                                    const f16* __restrict__ Wt2,
                                                    const float* __restrict__ b1,
                                                    const float* __restrict__ b2,
                                                    f16* __restrict__ Ch,
                                                    float* __restrict__ Cf) {
  __shared__ f16 Ws[2][128 * WROW];
  {
    const f16x8* g1 = (const f16x8*)Wt1;
    const f16x8* g2 = (const f16x8*)Wt2;
    for (int i = threadIdx.x; i < 2048; i += 512) {
      int c = i >> 4;
      int k8 = (i & 15) << 3;
      *(f16x8*)&Ws[0][c * WROW + k8] = g1[i];
      *(f16x8*)&Ws[1][c * WROW + k8] = g2[i];
    }
  }

  const int w = threadIdx.x >> 6;   // wave 0..7
  const int l = threadIdx.x & 63;
  const int l15 = l & 15;
  const int g = l >> 4;
  const int r0 = blockIdx.x * 128 + w * 16;

  // A-frags from global (overlaps W staging)
  const int arow = min(r0 + l15, N - 1);
  const f16* Arow = A + (size_t)arow * D;
  f16x8 a[4];
#pragma unroll
  for (int t = 0; t < 4; ++t)
    a[t] = *(const f16x8*)(Arow + t * 32 + g * 8);

  float bc1[8], bc2[8];
#pragma unroll
  for (int c = 0; c < 8; ++c) {
    bc1[c] = b1[c * 16 + l15];
    bc2[c] = b2[c * 16 + l15];
  }
  __syncthreads();  // W staged

  // ---- phase A: h = relu(A @ W1 + b1) ----
  f32x4 acc[8];
#pragma unroll
  for (int c = 0; c < 8; ++c) acc[c] = (f32x4){0.f, 0.f, 0.f, 0.f};
#pragma unroll
  for (int t = 0; t < 4; ++t) {
#pragma unroll
    for (int c = 0; c < 8; ++c) {
      f16x8 b = *(const f16x8*)&Ws[0][(c * 16 + l15) * WROW + t * 32 + g * 8];
      acc[c] = __builtin_amdgcn_mfma_f32_16x16x32_f16(a[t], b, acc[c], 0, 0, 0);
    }
  }
  __syncthreads();  // all waves done reading W1

  // h tile (128 x 128 f16) into W1's retired buffer
  f16* hbuf = &Ws[0][0];
#pragma unroll
  for (int r = 0; r < 4; ++r) {
    int hr = w * 16 + g * 4 + r;
#pragma unroll
    for (int c = 0; c < 8; ++c) {
      float vv = fmaxf(acc[c][r] + bc1[c], 0.0f);
      hbuf[hr * WROW + c * 16 + l15] = (f16)vv;
    }
  }
  __syncthreads();

  // ---- phase B: x' = relu(h @ W2 + b2) ----
  f16x8 a2[4];
#pragma unroll
  for (int t = 0; t < 4; ++t)
    a2[t] = *(const f16x8*)&hbuf[(w * 16 + l15) * WROW + t * 32 + g * 8];

#pragma unroll
  for (int c = 0; c < 8; ++c) acc[c] = (f32x4){0.f, 0.f, 0.f, 0.f};
#pragma unroll
  for (int t = 0; t < 4; ++t) {
#pragma unroll
    for (int c = 0; c < 8; ++c) {
      f16x8 b = *(const f16x8*)&Ws[1][(c * 16 + l15) * WROW + t * 32 + g * 8];
      acc[c] = __builtin_amdgcn_mfma_f32_16x16x32_f16(a2[t], b, acc[c], 0, 0, 0);
    }
  }

#pragma unroll
  for (int r = 0; r < 4; ++r) {
    int rr = r0 + g * 4 + r;
    if (rr < N) {
#pragma unroll
      for (int c = 0; c < 8; ++c) {
        int col = c * 16 + l15;
        float vv = fmaxf(acc[c][r] + bc2[c], 0.0f);
        if (Cf) Cf[(size_t)rr * D + col] = vv;      // final layer: f32 only
        else    Ch[(size_t)rr * D + col] = (f16)vv; // intermediate: f16 only
      }
    }
  }
}

extern "C" void kernel_launch(void* const* d_in, const int* in_sizes, int n_in,
                              void* d_out, int out_size, void* d_ws, size_t ws_size,
                              hipStream_t stream) {
  const float* x0 = (const float*)d_in[0];
  const int* ei   = (const int*)d_in[1];
  const float* W1 = (const float*)d_in[2];
  const float* b1 = (const float*)d_in[3];
  const float* W2 = (const float*)d_in[4];
  const float* b2 = (const float*)d_in[5];
  float* out = (float*)d_out;

  // workspace layout (f16 arrays, then int2 (8B-aligned), then ints)
  f16* xh      = (f16*)d_ws;                          // (N+1)*D (row N = zeros)
  f16* aggh    = xh + (size_t)(N + 1) * D;            // N*D
  f16* Wt      = aggh + (size_t)N * D;                // 2*L*D*D
  int2* srcdst = (int2*)(Wt + (size_t)2 * L * D * D); // E (8B aligned)
  int2* part   = srcdst + E;                          // E
  int2* offpe  = part + E;                            // N
  int* gcnt    = (int*)(offpe + N);                   // K*NAB
  int* ssrc    = gcnt + (size_t)K * NAB;              // E + K*SLACK (padded)

  const dim3 blk(256);

  // ---- one-time CSR build (zero global atomics) ----
  k_init<<<384 + 3125 + NAB + 1, blk, 0, stream>>>(x0, ei, W1, W2, Wt, xh,
                                                   srcdst, gcnt);
  k_scat<<<NAB, blk, 0, stream>>>(srcdst, gcnt, part);
  k_fin<<<K, blk, 0, stream>>>(part, gcnt, offpe, ssrc);

  const int gemm_blocks = (N + 127) / 128;  // 391
  const int gather_blocks = N / 16;         // 3125

  for (int l = 0; l < L; ++l) {
    k_gather_f16<<<gather_blocks, blk, 0, stream>>>(xh, offpe, ssrc, aggh);
    k_gemm_fused<<<gemm_blocks, dim3(512), 0, stream>>>(
        aggh, Wt + (size_t)l * D * D, Wt + (size_t)(L + l) * D * D,
        b1 + (size_t)l * D, b2 + (size_t)l * D, xh,
        (l == L - 1) ? out : nullptr);
  }
}

// Round 19
// 174.293 us; speedup vs baseline: 1.0864x; 1.0864x over previous
//
#include <hip/hip_runtime.h>
#include <cstdint>

// GIN: N=50000, D=128, E=800000, L=3.
// per layer: agg = x + gather-sum over CSR(dst); x' = relu(relu(agg@W1+b1)@W2+b2)
// CSR built once per launch with ZERO global atomics (rounds 8-10 lesson:
// scattered global atomics cap at ~16 line-ops/ns regardless of scope/layout).
// Round-19 = round-16 optimum restored (r17 perm and r18 ILP/occupancy bundle
// both regressed: gather is L3-service-bound, ~10 TB/s effective; scheduling
// tricks don't move it). Only retained tweak: off/offend packed as int2.
// Gather = 16 nodes/block x 16 lanes, branch-free 8-wide padded loop
// (lists padded to x8; dummy src = zeroed row N).
// GEMM = 512-thr, 128 rows, dual-W LDS staging (69.6 KB, 2 blocks/CU
// -> 16 waves/CU); h tile reuses W1's retired LDS buffer.

constexpr int N = 50000;
constexpr int D = 128;
constexpr int E = 800000;
constexpr int L = 3;
constexpr int WROW = 136;                 // padded LDS row (f16): 2-way banks, free
constexpr int PSH = 9;                    // partition shift: 512 nodes
constexpr int PN = 1 << PSH;              // 512
constexpr int K = (N + PN - 1) >> PSH;    // 98 partitions
constexpr int SLACK = 7 * PN;             // padded capacity slack per partition
constexpr int ABLK = 2048;                // edges per A-block
constexpr int NAB = (E + ABLK - 1) / ABLK;  // 391

typedef _Float16 f16;
typedef _Float16 f16x8 __attribute__((ext_vector_type(8)));
typedef float f32x4 __attribute__((ext_vector_type(4)));

// ---- edge index load (handles int32 or int64 storage) ----
__device__ __forceinline__ bool ei_is64(const int* ei) {
  return (ei[1] == 0) && (ei[3] == 0) && (ei[5] == 0);
}
__device__ __forceinline__ int ei_src(const int* ei, int e, bool is64) {
  return is64 ? ei[2 * (size_t)e] : ei[e];
}
__device__ __forceinline__ int ei_dst(const int* ei, int e, bool is64) {
  return is64 ? ei[2 * ((size_t)E + e)] : ei[(size_t)E + e];
}

// ---------------- merged one-time prep: wprep + cvt + edge pass A1 + zrow ----
// grid = 384 + 3125 + NAB + 1 blocks.
__global__ __launch_bounds__(256) void k_init(const float* __restrict__ x0,
                                              const int* __restrict__ ei,
                                              const float* __restrict__ W1,
                                              const float* __restrict__ W2,
                                              f16* __restrict__ Wt,
                                              f16* __restrict__ xh,
                                              int2* __restrict__ srcdst,
                                              int* __restrict__ gcnt) {
  __shared__ int hist[K];
  const int bid = blockIdx.x;
  if (bid < 384) {
    // Wt[m][c][k] = Wsrc[m][k][c] as f16 (first L from W1, rest W2)
    int i = bid * 256 + threadIdx.x;
    int m = i >> 14;
    int c = (i >> 7) & 127;
    int k = i & 127;
    const float* src = (m < L) ? (W1 + (size_t)m * D * D)
                               : (W2 + (size_t)(m - L) * D * D);
    Wt[i] = (f16)src[(size_t)k * D + c];
  } else if (bid < 384 + 3125) {
    // x0 f32 -> xh f16, 8 elems/thread
    int i = (bid - 384) * 256 + threadIdx.x;
    float4 v0 = *(const float4*)(x0 + (size_t)i * 8);
    float4 v1 = *(const float4*)(x0 + (size_t)i * 8 + 4);
    f16x8 o = {(f16)v0.x, (f16)v0.y, (f16)v0.z, (f16)v0.w,
               (f16)v1.x, (f16)v1.y, (f16)v1.z, (f16)v1.w};
    *(f16x8*)(xh + (size_t)i * 8) = o;
  } else if (bid < 384 + 3125 + NAB) {
    // edges -> int2(src,dst) + LDS partition histogram (no global atomics)
    const int b = bid - (384 + 3125);
    for (int i = threadIdx.x; i < K; i += 256) hist[i] = 0;
    __syncthreads();
    const int base = b * ABLK;
    const int nHere = min(ABLK, E - base);
    bool is64 = ei_is64(ei);
#pragma unroll
    for (int r = 0; r < ABLK / 256; ++r) {
      int idx = r * 256 + threadIdx.x;
      if (idx < nHere) {
        int e = base + idx;
        int s = ei_src(ei, e, is64);
        int d = ei_dst(ei, e, is64);
        srcdst[e] = make_int2(s, d);
        atomicAdd(&hist[d >> PSH], 1);  // LDS atomic
      }
    }
    __syncthreads();
    for (int i = threadIdx.x; i < K; i += 256) gcnt[i * NAB + b] = hist[i];
  } else {
    // zero row N of xh (dummy gather target for padded neighbor lists)
    if (threadIdx.x < 16)
      *(f16x8*)(xh + (size_t)N * D + threadIdx.x * 8) = (f16x8){};
  }
}

// ---------------- per-partition prefix over block counts ----------------
__global__ __launch_bounds__(256) void k_gbase(const int* __restrict__ gcnt,
                                               int* __restrict__ gbase,
                                               int* __restrict__ psize) {
  __shared__ int s[256];
  __shared__ int carry;
  const int p = blockIdx.x;
  const int tid = threadIdx.x;
  if (tid == 0) carry = 0;
  __syncthreads();
  for (int chunk = 0; chunk < 2; ++chunk) {  // 2*256 >= NAB
    int i = chunk * 256 + tid;
    int v = (i < NAB) ? gcnt[p * NAB + i] : 0;
    s[tid] = v;
    __syncthreads();
#pragma unroll
    for (int o = 1; o < 256; o <<= 1) {
      int t = (tid >= o) ? s[tid - o] : 0;
      __syncthreads();
      s[tid] += t;
      __syncthreads();
    }
    int excl = s[tid] - v + carry;
    if (i < NAB) gbase[p * NAB + i] = excl;
    __syncthreads();
    if (tid == 255) carry = carry + s[255];
    __syncthreads();
  }
  if (tid == 0) psize[p] = carry;
}

// in-block 98-entry exclusive prefix of psize (thread-0 serial; tiny)
__device__ __forceinline__ void pscan_inblock(const int* __restrict__ psize,
                                              int* __restrict__ pb) {
  const int tid = threadIdx.x;
  if (tid < K) pb[tid] = psize[tid];
  __syncthreads();
  if (tid == 0) {
    int r = 0;
    for (int i = 0; i < K; ++i) {
      int v = pb[i];
      pb[i] = r;
      r += v;
    }
  }
  __syncthreads();
}

// ---------------- scatter edges into partition-contiguous part[] ----------------
__global__ __launch_bounds__(256) void k_scat(const int2* __restrict__ srcdst,
                                              const int* __restrict__ gbase,
                                              const int* __restrict__ psize,
                                              int2* __restrict__ part) {
  __shared__ int rankc[K];
  __shared__ int pb[K];
  const int b = blockIdx.x;
  const int tid = threadIdx.x;
  for (int i = tid; i < K; i += 256) rankc[i] = 0;
  pscan_inblock(psize, pb);
  const int base = b * ABLK;
  const int nHere = min(ABLK, E - base);
#pragma unroll
  for (int r = 0; r < ABLK / 256; ++r) {
    int idx = r * 256 + tid;
    if (idx < nHere) {
      int2 sd = srcdst[base + idx];
      int p = sd.y >> PSH;
      int lr = atomicAdd(&rankc[p], 1);  // LDS atomic
      part[pb[p] + gbase[p * NAB + b] + lr] = sd;
    }
  }
}

// ---------------- finalize: padded offpe + windowed ssrc scatter -------
// node n: ssrc[offpe[n].x .. offpe[n].y) with length ceil(deg/8)*8; pad slots
// filled with N (zero row). Partition p's padded window starts at
// pb[p] + p*SLACK (capacity psize[p]+SLACK >= padded content).
__global__ __launch_bounds__(256) void k_fin(const int2* __restrict__ part,
                                             const int* __restrict__ psize,
                                             int2* __restrict__ offpe,
                                             int* __restrict__ ssrc) {
  __shared__ int hist[PN];
  __shared__ int bbase[PN];
  __shared__ int rc[PN];
  __shared__ int s[256];
  __shared__ int pb[K];
  __shared__ int carry;
  const int p = blockIdx.x;
  const int tid = threadIdx.x;
  const int lo = p << PSH;
  const int nn = min(PN, N - lo);
  for (int i = tid; i < PN; i += 256) { hist[i] = 0; rc[i] = 0; }
  if (tid == 0) carry = 0;
  pscan_inblock(psize, pb);
  const int ebeg = pb[p], eend = pb[p] + psize[p];
  const int padbase = pb[p] + p * SLACK;
  for (int e = ebeg + tid; e < eend; e += 256)
    atomicAdd(&hist[part[e].y - lo], 1);  // LDS atomic
  __syncthreads();
  // exclusive scan of PADDED degrees -> bbase
  for (int chunk = 0; chunk < PN / 256; ++chunk) {
    int i = chunk * 256 + tid;
    int v = (hist[i] + 7) & ~7;  // padded degree
    s[tid] = v;
    __syncthreads();
#pragma unroll
    for (int o = 1; o < 256; o <<= 1) {
      int t = (tid >= o) ? s[tid - o] : 0;
      __syncthreads();
      s[tid] += t;
      __syncthreads();
    }
    bbase[i] = s[tid] - v + carry;
    __syncthreads();
    if (tid == 255) carry = carry + s[255];
    __syncthreads();
  }
  // offpe + pad fill
  for (int i = tid; i < nn; i += 256) {
    int st = padbase + bbase[i];
    int deg = hist[i];
    int pd = (deg + 7) & ~7;
    offpe[lo + i] = make_int2(st, st + pd);
    for (int j = deg; j < pd; ++j) ssrc[st + j] = N;  // dummy -> zero row
  }
  __syncthreads();
  // scatter real entries
  for (int e = ebeg + tid; e < eend; e += 256) {
    int2 sd = part[e];
    int b = sd.y - lo;
    int r = atomicAdd(&rc[b], 1);  // LDS atomic
    ssrc[padbase + bbase[b] + r] = sd.x;
  }
}

// ---------------- gather-aggregate (f16): agg[n] = x[n] + sum_{j} x[src_j]
// 16 nodes/block x 16 lanes; lane owns 8 dims (16B); branch-free 8-wide loop
// (lists padded to x8; dummies hit zeroed row N).
__global__ __launch_bounds__(256) void k_gather_f16(const f16* __restrict__ x,
                                                    const int2* __restrict__ offpe,
                                                    const int* __restrict__ ssrc,
                                                    f16* __restrict__ agg) {
  const int n = blockIdx.x * 16 + (threadIdx.x >> 4);
  const int d0 = (threadIdx.x & 15) << 3;
  f16x8 v = *(const f16x8*)(x + (size_t)n * D + d0);
  float acc[8];
#pragma unroll
  for (int j = 0; j < 8; ++j) acc[j] = (float)v[j];
  const int2 oe = offpe[n];
  for (int p = oe.x; p < oe.y; p += 8) {
    f16x8 u[8];
#pragma unroll
    for (int q = 0; q < 8; ++q) {
      int s = ssrc[p + q];
      u[q] = *(const f16x8*)(x + (size_t)s * D + d0);
    }
#pragma unroll
    for (int q = 0; q < 8; ++q)
#pragma unroll
      for (int j = 0; j < 8; ++j) acc[j] += (float)u[q][j];
  }
  f16x8 o;
#pragma unroll
  for (int j = 0; j < 8; ++j) o[j] = (f16)acc[j];
  *(f16x8*)(agg + (size_t)n * D + d0) = o;
}

// ---------------- fused double MFMA GEMM + bias + ReLU ----------------
// x' = relu(relu(A@W1+b1)@W2+b2). A f16 row-major; Wt* f16 [col][k].
// Block: 512 thr = 8 waves, 128 rows (16/wave). Dual-W LDS (69.6 KB,
// 2 blocks/CU -> 16 waves/CU = 4/SIMD). h (128x136 f16 = 34.8 KB) reuses
// W1's retired buffer. Intermediate layers write f16; last layer f32 only.
__global__ __launch_bounds__(512) void k_gemm_fused(const f16* __restrict__ A,
                                                    const f16* __restrict__ Wt1,
                                                    const f16* __restrict__ Wt2,
                                                    const float* __restrict__ b1,
                                                    const float* __restrict__ b2,
                                                    f16* __restrict__ Ch,
                                                    float* __restrict__ Cf) {
  __shared__ f16 Ws[2][128 * WROW];
  {
    const f16x8* g1 = (const f16x8*)Wt1;
    const f16x8* g2 = (const f16x8*)Wt2;
    for (int i = threadIdx.x; i < 2048; i += 512) {
      int c = i >> 4;
      int k8 = (i & 15) << 3;
      *(f16x8*)&Ws[0][c * WROW + k8] = g1[i];
      *(f16x8*)&Ws[1][c * WROW + k8] = g2[i];
    }
  }

  const int w = threadIdx.x >> 6;   // wave 0..7
  const int l = threadIdx.x & 63;
  const int l15 = l & 15;
  const int g = l >> 4;
  const int r0 = blockIdx.x * 128 + w * 16;

  // A-frags from global (overlaps W staging)
  const int arow = min(r0 + l15, N - 1);
  const f16* Arow = A + (size_t)arow * D;
  f16x8 a[4];
#pragma unroll
  for (int t = 0; t < 4; ++t)
    a[t] = *(const f16x8*)(Arow + t * 32 + g * 8);

  float bc1[8], bc2[8];
#pragma unroll
  for (int c = 0; c < 8; ++c) {
    bc1[c] = b1[c * 16 + l15];
    bc2[c] = b2[c * 16 + l15];
  }
  __syncthreads();  // W staged

  // ---- phase A: h = relu(A @ W1 + b1) ----
  f32x4 acc[8];
#pragma unroll
  for (int c = 0; c < 8; ++c) acc[c] = (f32x4){0.f, 0.f, 0.f, 0.f};
#pragma unroll
  for (int t = 0; t < 4; ++t) {
#pragma unroll
    for (int c = 0; c < 8; ++c) {
      f16x8 b = *(const f16x8*)&Ws[0][(c * 16 + l15) * WROW + t * 32 + g * 8];
      acc[c] = __builtin_amdgcn_mfma_f32_16x16x32_f16(a[t], b, acc[c], 0, 0, 0);
    }
  }
  __syncthreads();  // all waves done reading W1

  // h tile (128 x 128 f16) into W1's retired buffer
  f16* hbuf = &Ws[0][0];
#pragma unroll
  for (int r = 0; r < 4; ++r) {
    int hr = w * 16 + g * 4 + r;
#pragma unroll
    for (int c = 0; c < 8; ++c) {
      float vv = fmaxf(acc[c][r] + bc1[c], 0.0f);
      hbuf[hr * WROW + c * 16 + l15] = (f16)vv;
    }
  }
  __syncthreads();

  // ---- phase B: x' = relu(h @ W2 + b2) ----
  f16x8 a2[4];
#pragma unroll
  for (int t = 0; t < 4; ++t)
    a2[t] = *(const f16x8*)&hbuf[(w * 16 + l15) * WROW + t * 32 + g * 8];

#pragma unroll
  for (int c = 0; c < 8; ++c) acc[c] = (f32x4){0.f, 0.f, 0.f, 0.f};
#pragma unroll
  for (int t = 0; t < 4; ++t) {
#pragma unroll
    for (int c = 0; c < 8; ++c) {
      f16x8 b = *(const f16x8*)&Ws[1][(c * 16 + l15) * WROW + t * 32 + g * 8];
      acc[c] = __builtin_amdgcn_mfma_f32_16x16x32_f16(a2[t], b, acc[c], 0, 0, 0);
    }
  }

#pragma unroll
  for (int r = 0; r < 4; ++r) {
    int rr = r0 + g * 4 + r;
    if (rr < N) {
#pragma unroll
      for (int c = 0; c < 8; ++c) {
        int col = c * 16 + l15;
        float vv = fmaxf(acc[c][r] + bc2[c], 0.0f);
        if (Cf) Cf[(size_t)rr * D + col] = vv;      // final layer: f32 only
        else    Ch[(size_t)rr * D + col] = (f16)vv; // intermediate: f16 only
      }
    }
  }
}

extern "C" void kernel_launch(void* const* d_in, const int* in_sizes, int n_in,
                              void* d_out, int out_size, void* d_ws, size_t ws_size,
                              hipStream_t stream) {
  const float* x0 = (const float*)d_in[0];
  const int* ei   = (const int*)d_in[1];
  const float* W1 = (const float*)d_in[2];
  const float* b1 = (const float*)d_in[3];
  const float* W2 = (const float*)d_in[4];
  const float* b2 = (const float*)d_in[5];
  float* out = (float*)d_out;

  // workspace layout (f16 arrays, then int2 (8B-aligned), then ints)
  f16* xh      = (f16*)d_ws;                          // (N+1)*D (row N = zeros)
  f16* aggh    = xh + (size_t)(N + 1) * D;            // N*D
  f16* Wt      = aggh + (size_t)N * D;                // 2*L*D*D
  int2* srcdst = (int2*)(Wt + (size_t)2 * L * D * D); // E (8B aligned)
  int2* part   = srcdst + E;                          // E
  int2* offpe  = part + E;                            // N
  int* gcnt    = (int*)(offpe + N);                   // K*NAB
  int* gbase   = gcnt + (size_t)K * NAB;              // K*NAB
  int* psize   = gbase + (size_t)K * NAB;             // K
  int* ssrc    = psize + K;                           // E + K*SLACK (padded)

  const dim3 blk(256);

  // ---- one-time CSR build (zero global atomics) ----
  k_init<<<384 + 3125 + NAB + 1, blk, 0, stream>>>(x0, ei, W1, W2, Wt, xh,
                                                   srcdst, gcnt);
  k_gbase<<<K, blk, 0, stream>>>(gcnt, gbase, psize);
  k_scat<<<NAB, blk, 0, stream>>>(srcdst, gbase, psize, part);
  k_fin<<<K, blk, 0, stream>>>(part, psize, offpe, ssrc);

  const int gemm_blocks = (N + 127) / 128;  // 391
  const int gather_blocks = N / 16;         // 3125

  for (int l = 0; l < L; ++l) {
    k_gather_f16<<<gather_blocks, blk, 0, stream>>>(xh, offpe, ssrc, aggh);
    k_gemm_fused<<<gemm_blocks, dim3(512), 0, stream>>>(
        aggh, Wt + (size_t)l * D * D, Wt + (size_t)(L + l) * D * D,
        b1 + (size_t)l * D, b2 + (size_t)l * D, xh,
        (l == L - 1) ? out : nullptr);
  }
}